// Round 1
// baseline (250.327 us; speedup 1.0000x reference)
//
#include <hip/hip_runtime.h>
#include <hip/hip_bf16.h>
#include <hip/hip_fp16.h>
#include <math.h>

// Problem constants (B,S,H,M) = (8,128,768,128)
#define B_   8
#define S_   128
#define H_   768
#define M_   128
#define P_   8256      // S*(S+1)/2 pairs per batch
#define BP_  66048     // B_ * P_
#define EPSF 1e-12f

typedef unsigned short u16;
typedef unsigned int   u32;
typedef _Float16 h16;
typedef _Float16 ffrag __attribute__((ext_vector_type(8)));   // 8 f16 = 4 VGPR
typedef float    f32x4 __attribute__((ext_vector_type(4)));

// packed f16 fma: one v_pk_fma_f16 for two lanes
__device__ __forceinline__ u32 fuse2(u32 x, u32 g, u32 b) {
    __half2 r = __hfma2(__builtin_bit_cast(__half2, x),
                        __builtin_bit_cast(__half2, g),
                        __builtin_bit_cast(__half2, b));
    return __builtin_bit_cast(u32, r);
}
// tanh(x) = 1 - 2/(e^{2x}+1): exp + rcp + fma, branch/copysign-free,
// correct at +-inf (rcp(inf)=0 -> 1; exp(-inf)=0 -> -1)
__device__ __forceinline__ float fast_tanh(float v) {
    float t = __expf(v + v);
    float r = __builtin_amdgcn_rcpf(t + 1.0f);
    return fmaf(-2.0f, r, 1.0f);
}
// async global->LDS 16B per lane; lds dst must be the wave-uniform base
__device__ __forceinline__ void gl_lds16(const h16* g, h16* l) {
    __builtin_amdgcn_global_load_lds(
        (const __attribute__((address_space(1))) u32*)g,
        (__attribute__((address_space(3))) u32*)l, 16, 0, 0);
}

// ============ kernel A: weight convert + wct transpose + per-row normalize ============
// blocks [0,4610): convert wgb/wbb (f32->f16, coalesced) + biasc
// blocks [4610,4682): wct[n][h] build via 64x64 LDS transpose tile (both global
//                     accesses coalesced; old path read w at stride 512B = 64
//                     lines/wave)
// blocks [4682,5706): row normalize; xn = (x-mean)/(var+eps)^2 (ref squares, no sqrt)
#define CONVN 4610
#define WCT0  4610
#define NORM0 4682
__global__ void k_prep(const float* __restrict__ seq,
                       const float* __restrict__ wg, const float* __restrict__ wb,
                       const float* __restrict__ we, const float* __restrict__ wh,
                       const float* __restrict__ wt,
                       const float* __restrict__ be, const float* __restrict__ bh,
                       const float* __restrict__ bt,
                       h16* __restrict__ wgb, h16* __restrict__ wbb,
                       h16* __restrict__ wct, float* __restrict__ biasc,
                       h16* __restrict__ xn, h16* __restrict__ condb)
{
    __shared__ float red[4];
    __shared__ float tile[64][65];
    const int bx = blockIdx.x;
    const int t = threadIdx.x;

    if (bx < CONVN) {   // ---- convert wgb / wbb / biasc (all coalesced) ----
        int idx = bx * 256 + t;
        if (idx < 589824) {
            wgb[idx] = (h16)wg[idx];
        } else if (idx < 1179648) {
            int i = idx - 589824;
            wbb[i] = (h16)wb[i];
        } else if (idx < 1180032) {
            int n = idx - 1179648;
            biasc[n] = (n < 128) ? be[n] : (n < 256 ? bh[n - 128] : bt[n - 256]);
        }
        return;
    }
    if (bx < NORM0) {   // ---- wct transpose: wct[n][h] = w_x[h][m], n = x*128+m ----
        int b = bx - WCT0;                 // [0,72)
        int x = b / 24, rem = b - x * 24;  // 3 weights x (2 m-tiles x 12 h-tiles)
        int mt = rem / 12, ht = rem - mt * 12;
        int m0 = mt * 64, h0 = ht * 64;
        const float* w = (x == 0) ? we : (x == 1 ? wh : wt);
        int mm = t & 63, hh4 = t >> 6;
#pragma unroll
        for (int r2 = 0; r2 < 16; ++r2) {
            int hh = hh4 + r2 * 4;
            tile[hh][mm] = w[(size_t)(h0 + hh) * 128 + m0 + mm];   // coalesced read
        }
        __syncthreads();
        int hh2 = t & 63, nn4 = t >> 6;
#pragma unroll
        for (int r2 = 0; r2 < 16; ++r2) {
            int nn = nn4 + r2 * 4;
            int n = x * 128 + m0 + nn;
            wct[(size_t)n * H_ + h0 + hh2] = (h16)tile[hh2][nn];   // coalesced write
        }
        return;
    }
    // ---- normalize ----
    const int row = bx - NORM0;
    const int lane = t & 63, wid = t >> 6;
    const float* x = seq + (size_t)row * H_;
    float x0 = x[t], x1 = x[t + 256], x2 = x[t + 512];

    float s = x0 + x1 + x2;
    for (int o = 32; o; o >>= 1) s += __shfl_xor(s, o);
    if (lane == 0) red[wid] = s;
    __syncthreads();
    float mean = (red[0] + red[1] + red[2] + red[3]) * (1.0f / 768.0f);

    float c0 = x0 - mean, c1 = x1 - mean, c2 = x2 - mean;
    float ss = c0 * c0 + c1 * c1 + c2 * c2;
    for (int o = 32; o; o >>= 1) ss += __shfl_xor(ss, o);
    __syncthreads();
    if (lane == 0) red[wid] = ss;
    __syncthreads();
    float var = (red[0] + red[1] + red[2] + red[3]) * (1.0f / 768.0f);
    float sd = var + EPSF;
    float scale = 1.0f / (sd * sd);

    h16* xr = xn + (size_t)row * H_;
    h16* cr = condb + (size_t)row * H_;
    xr[t] = (h16)(c0 * scale); xr[t + 256] = (h16)(c1 * scale); xr[t + 512] = (h16)(c2 * scale);
    cr[t] = (h16)x0;           cr[t + 256] = (h16)x1;           cr[t + 512] = (h16)x2;
}

// ============ kernel B: cond GEMM -> gamma_c / beta_c (f16) ============
// C[p][o] = sum_h cond[p][h] * W[o][h] + bias[o];  tiles 64x64, BK=64
// grid (16, 24): by<12 -> gamma cols by*64 ; else beta cols (by-12)*64
// LDS stride 72 h16 = 144 B: addr%128 takes 8 values over 16 rows -> conflict-free
__global__ __launch_bounds__(256) void k_cond_gemm(
    const h16* __restrict__ Ab, const h16* __restrict__ Wg, const h16* __restrict__ Wb,
    const float* __restrict__ gamma, const float* __restrict__ beta,
    h16* __restrict__ Gc, h16* __restrict__ Bc)
{
    __shared__ h16 Ash[64 * 72];
    __shared__ h16 Bsh[64 * 72];
    const int t = threadIdx.x;
    const int row0 = blockIdx.x * 64;
    const int by = blockIdx.y;
    const bool isg = (by < 12);
    const int nc0 = (isg ? by : by - 12) * 64;
    const h16* wsrc = isg ? Wg : Wb;

    const int r = t >> 2, q = t & 3;
    const h16* ap = Ab + (size_t)(row0 + r) * H_ + q * 16;
    const h16* wp = wsrc + (size_t)(nc0 + r) * H_ + q * 16;
    h16* asto = &Ash[r * 72 + q * 16];
    h16* bsto = &Bsh[r * 72 + q * 16];

    const int lane = t & 63, wid = t >> 6;
    const int wm0 = (wid >> 1) * 32, wn0 = (wid & 1) * 32;
    const int l15 = lane & 15, quad = lane >> 4, q8 = quad * 8;

    f32x4 acc[2][2] = {};
    for (int kt = 0; kt < 12; ++kt) {
        const int k0 = kt * 64;
        uint4 a0 = *(const uint4*)(ap + k0); uint4 a1 = *(const uint4*)(ap + k0 + 8);
        uint4 w0 = *(const uint4*)(wp + k0); uint4 w1 = *(const uint4*)(wp + k0 + 8);
        *(uint4*)asto = a0; *(uint4*)(asto + 8) = a1;
        *(uint4*)bsto = w0; *(uint4*)(bsto + 8) = w1;
        __syncthreads();
#pragma unroll
        for (int ks = 0; ks < 64; ks += 32) {
            ffrag af[2], bf[2];
#pragma unroll
            for (int mi = 0; mi < 2; ++mi)
                af[mi] = *reinterpret_cast<const ffrag*>(&Ash[(wm0 + mi * 16 + l15) * 72 + ks + q8]);
#pragma unroll
            for (int ni = 0; ni < 2; ++ni)
                bf[ni] = *reinterpret_cast<const ffrag*>(&Bsh[(wn0 + ni * 16 + l15) * 72 + ks + q8]);
#pragma unroll
            for (int mi = 0; mi < 2; ++mi)
#pragma unroll
                for (int ni = 0; ni < 2; ++ni)
                    acc[mi][ni] = __builtin_amdgcn_mfma_f32_16x16x32_f16(af[mi], bf[ni], acc[mi][ni], 0, 0, 0);
        }
        __syncthreads();
    }

    const float* bias = isg ? gamma : beta;
    h16* outp = isg ? Gc : Bc;
#pragma unroll
    for (int mi = 0; mi < 2; ++mi)
#pragma unroll
        for (int ni = 0; ni < 2; ++ni) {
            int c = wn0 + ni * 16 + l15;
            float bv = bias[nc0 + c];
#pragma unroll
            for (int reg = 0; reg < 4; ++reg) {
                int rg = wm0 + mi * 16 + quad * 4 + reg;   // C/D: col=lane&15, row=quad*4+reg (m89)
                outp[(size_t)(row0 + rg) * H_ + nc0 + c] = (h16)(acc[mi][ni][reg] + bv);
            }
        }
}

// ============ kernel C: fused pair GEMM ============
// out[head, gp, m] = tanh( (xn[b,j]*gc[b,i] + bc[b,i]) @ W[:, cg] + biasc[cg] )
// Block 64 rows x 192 cols, BK=32, 24 iters, double-buffered.
// v2: wave tile shrunk 64x96 -> 64x48 (acc[4][3]=48 regs instead of 96) so
// 3 blocks/CU fit (launch_bounds(256,3), LDS 33KB) -> 12 waves/CU of
// INDEPENDENT barrier groups. Previous 2-block lockstep exposed every
// load-latency + barrier drain (MfmaUtil 11.5%, Occ 17%).
// LDS is CHUNK-MAJOR: slot(chunk,row) at (chunk*ROWS+row)*8 h16 — every
// fragment ds_read_b128 is 16 lanes x contiguous 16B, and B-DMA
// (wave-uniform base + lane*16) maps to lane-linear slots.
__global__ __launch_bounds__(256, 3) void k_pair_gemm(
    const h16* __restrict__ Xn, const h16* __restrict__ Gcb, const h16* __restrict__ Bcb,
    const h16* __restrict__ WcT, const float* __restrict__ biasc,
    float* __restrict__ out)
{
    __shared__ h16 Ash[2][4 * 64 * 8];    // 4 KB per buf
    __shared__ h16 Bsh[2][4 * 192 * 8];   // 12 KB per buf
    __shared__ int offx[64];              // xn row index (b*128 + j)
    __shared__ int offc[64];              // cond row index (b*128 + i)

    const int t = threadIdx.x;
    const int row0 = blockIdx.x * 64;
    const int nb = blockIdx.y;            // 0/1 -> cols [0,192) / [192,384)

    if (t < 64) {
        int gp = row0 + t;
        int b = gp / P_;
        int p = gp - b * P_;
        int i = (int)((257.0f - sqrtf(66049.0f - 8.0f * (float)p)) * 0.5f);
        if (i < 0) i = 0; if (i > 127) i = 127;
        while (i > 0 && (i * (257 - i)) / 2 > p) --i;
        while (((i + 1) * (256 - i)) / 2 <= p) ++i;
        int j = i + (p - (i * (257 - i)) / 2);
        offx[t] = b * 128 + j;
        offc[t] = b * 128 + i;
    }
    __syncthreads();

    // A staging: thread covers row r=t>>2, chunk c4=t&3 (8 h16 at k-offset c4*8)
    const int r = t >> 2, c4 = t & 3;
    const h16* xp  = Xn  + (size_t)offx[r] * H_ + c4 * 8;
    const h16* gp_ = Gcb + (size_t)offc[r] * H_ + c4 * 8;
    const h16* bp_ = Bcb + (size_t)offc[r] * H_ + c4 * 8;
    const int aw = (c4 * 64 + r) * 8;

    // B DMA: slot L = c*256+t in [0,768): chunk = L/192, n = L%192
    const h16* wbase = WcT + (size_t)nb * 192 * H_;
    const int wud = t & ~63;
    const h16* dsrc[3];
#pragma unroll
    for (int c = 0; c < 3; ++c) {
        int L = c * 256 + t;
        int ch = L / 192, n = L - ch * 192;
        dsrc[c] = wbase + (size_t)n * H_ + ch * 8;
    }

    const int lane = t & 63, wid = t >> 6;
    const int wn0 = wid * 48;             // 4 waves x 48 cols
    const int l15 = lane & 15, quad = lane >> 4;

    // ---------- prologue: stage kt=0 into buffer 0 ----------
#pragma unroll
    for (int c = 0; c < 3; ++c)
        gl_lds16(dsrc[c], &Bsh[0][(c * 256 + wud) * 8]);
    {
        uint4 xa = *(const uint4*)xp;
        uint4 ga = *(const uint4*)gp_;
        uint4 ba = *(const uint4*)bp_;
        uint4 f;
        f.x = fuse2(xa.x, ga.x, ba.x); f.y = fuse2(xa.y, ga.y, ba.y);
        f.z = fuse2(xa.z, ga.z, ba.z); f.w = fuse2(xa.w, ga.w, ba.w);
        *(uint4*)&Ash[0][aw] = f;
    }
    __syncthreads();

    f32x4 acc[4][3] = {};
#pragma unroll 2
    for (int kt = 0; kt < 24; ++kt) {
        const int buf = kt & 1, nbf = buf ^ 1;
        uint4 xa, ga, ba;
        if (kt < 23) {
            const int k0 = (kt + 1) * 32;
            // next-B DMA first (longest latency), then next-A loads
#pragma unroll
            for (int c = 0; c < 3; ++c)
                gl_lds16(dsrc[c] + k0, &Bsh[nbf][(c * 256 + wud) * 8]);
            xa = *(const uint4*)(xp + k0);
            ga = *(const uint4*)(gp_ + k0);
            ba = *(const uint4*)(bp_ + k0);
        }

        ffrag af[4], bf[3];
#pragma unroll
        for (int mi = 0; mi < 4; ++mi)
            af[mi] = *reinterpret_cast<const ffrag*>(&Ash[buf][(quad * 64 + mi * 16 + l15) * 8]);
#pragma unroll
        for (int ni = 0; ni < 3; ++ni)
            bf[ni] = *reinterpret_cast<const ffrag*>(&Bsh[buf][(quad * 192 + wn0 + ni * 16 + l15) * 8]);
#pragma unroll
        for (int mi = 0; mi < 4; ++mi)
#pragma unroll
            for (int ni = 0; ni < 3; ++ni)
                acc[mi][ni] = __builtin_amdgcn_mfma_f32_16x16x32_f16(af[mi], bf[ni], acc[mi][ni], 0, 0, 0);

        if (kt < 23) {
            uint4 f;
            f.x = fuse2(xa.x, ga.x, ba.x); f.y = fuse2(xa.y, ga.y, ba.y);
            f.z = fuse2(xa.z, ga.z, ba.z); f.w = fuse2(xa.w, ga.w, ba.w);
            *(uint4*)&Ash[nbf][aw] = f;
        }
        __syncthreads();
    }

    // epilogue: bias + tanh + store
#pragma unroll
    for (int mi = 0; mi < 4; ++mi)
#pragma unroll
        for (int ni = 0; ni < 3; ++ni) {
            int cg = nb * 192 + wn0 + ni * 16 + l15;
            int head = cg >> 7, m = cg & 127;
            float bv = biasc[cg];
#pragma unroll
            for (int reg = 0; reg < 4; ++reg) {
                int rg = mi * 16 + quad * 4 + reg;
                out[((size_t)head * BP_ + row0 + rg) * M_ + m] = fast_tanh(acc[mi][ni][reg] + bv);
            }
        }
}

extern "C" void kernel_launch(void* const* d_in, const int* in_sizes, int n_in,
                              void* d_out, int out_size, void* d_ws, size_t ws_size,
                              hipStream_t stream)
{
    const float* seq     = (const float*)d_in[0];
    const float* gamma   = (const float*)d_in[1];
    const float* beta    = (const float*)d_in[2];
    const float* w_beta  = (const float*)d_in[3];
    const float* w_gamma = (const float*)d_in[4];
    const float* w_ent   = (const float*)d_in[5];
    const float* b_ent   = (const float*)d_in[6];
    const float* w_head  = (const float*)d_in[7];
    const float* b_head  = (const float*)d_in[8];
    const float* w_tail  = (const float*)d_in[9];
    const float* b_tail  = (const float*)d_in[10];
    float* out = (float*)d_out;

    // workspace layout (all 16B-aligned)
    char* ws = (char*)d_ws;
    h16* xn    = (h16*)ws; ws += (size_t)1024 * 768 * 2;  // normalized rows, f16
    h16* condb = (h16*)ws; ws += (size_t)1024 * 768 * 2;  // seq as f16
    h16* wgb   = (h16*)ws; ws += (size_t)768 * 768 * 2;   // w_gamma f16 [o][h]
    h16* wbb   = (h16*)ws; ws += (size_t)768 * 768 * 2;   // w_beta  f16 [o][h]
    h16* wct   = (h16*)ws; ws += (size_t)384 * 768 * 2;   // [n][h] combined ent|head|tail
    h16* gc    = (h16*)ws; ws += (size_t)1024 * 768 * 2;  // gamma_c f16
    h16* bc    = (h16*)ws; ws += (size_t)1024 * 768 * 2;  // beta_c  f16
    float* biasc = (float*)ws; ws += 384 * 4;             // [ent|head|tail] bias

    hipLaunchKernelGGL(k_prep, dim3(NORM0 + 1024), dim3(256), 0, stream,
                       seq, w_gamma, w_beta, w_ent, w_head, w_tail,
                       b_ent, b_head, b_tail, wgb, wbb, wct, biasc, xn, condb);
    hipLaunchKernelGGL(k_cond_gemm, dim3(16, 24), dim3(256), 0, stream,
                       condb, wgb, wbb, gamma, beta, gc, bc);
    hipLaunchKernelGGL(k_pair_gemm, dim3(1032, 2), dim3(256), 0, stream,
                       xn, gc, bc, wct, biasc, out);
}

// Round 2
// 212.554 us; speedup vs baseline: 1.1777x; 1.1777x over previous
//
#include <hip/hip_runtime.h>
#include <hip/hip_bf16.h>
#include <hip/hip_fp16.h>
#include <math.h>

// Problem constants (B,S,H,M) = (8,128,768,128)
#define B_   8
#define S_   128
#define H_   768
#define M_   128
#define P_   8256      // S*(S+1)/2 pairs per batch
#define BP_  66048     // B_ * P_
#define EPSF 1e-12f

typedef unsigned short u16;
typedef unsigned int   u32;
typedef _Float16 h16;
typedef _Float16 ffrag __attribute__((ext_vector_type(8)));   // 8 f16 = 4 VGPR
typedef float    f32x4 __attribute__((ext_vector_type(4)));

// packed f16 fma: one v_pk_fma_f16 for two lanes
__device__ __forceinline__ u32 fuse2(u32 x, u32 g, u32 b) {
    __half2 r = __hfma2(__builtin_bit_cast(__half2, x),
                        __builtin_bit_cast(__half2, g),
                        __builtin_bit_cast(__half2, b));
    return __builtin_bit_cast(u32, r);
}
// tanh(x) = 1 - 2/(e^{2x}+1): exp + rcp + fma, branch/copysign-free,
// correct at +-inf (rcp(inf)=0 -> 1; exp(-inf)=0 -> -1)
__device__ __forceinline__ float fast_tanh(float v) {
    float t = __expf(v + v);
    float r = __builtin_amdgcn_rcpf(t + 1.0f);
    return fmaf(-2.0f, r, 1.0f);
}
// async global->LDS 16B per lane; lds dst must be the wave-uniform base
__device__ __forceinline__ void gl_lds16(const h16* g, h16* l) {
    __builtin_amdgcn_global_load_lds(
        (const __attribute__((address_space(1))) u32*)g,
        (__attribute__((address_space(3))) u32*)l, 16, 0, 0);
}

// ============ kernel A: weight convert + B-prepack + per-row normalize ============
// blocks [0,5763): convert fp32 weights -> f16:
//   [0,589824)          wgb  = w_gamma f16
//   [589824,1179648)    wbb  = w_beta  f16
//   [1179648,1474560)   wpk  = pre-packed pair-GEMM B tiles: for (nb,kt) a
//                       24KB contiguous image in chunk-major LDS slot order
//                       (ch*192+n)*8, ch=k-octet.  This makes the pair-GEMM's
//                       global_load_lds perfectly coalesced (8 lines/instr
//                       instead of 64: old layout strode 1536B per lane).
//   [1474560,1474944)   biasc
// blocks [5763, 5763+1024): row normalize; xn = (x-mean)/(var+eps)^2
#define NORM0 5763
__global__ void k_prep(const float* __restrict__ seq,
                       const float* __restrict__ wg, const float* __restrict__ wb,
                       const float* __restrict__ we, const float* __restrict__ wh,
                       const float* __restrict__ wt,
                       const float* __restrict__ be, const float* __restrict__ bh,
                       const float* __restrict__ bt,
                       h16* __restrict__ wgb, h16* __restrict__ wbb,
                       h16* __restrict__ wpk, float* __restrict__ biasc,
                       h16* __restrict__ xn, h16* __restrict__ condb)
{
    __shared__ float red[4];
    const int bx = blockIdx.x;
    const int t = threadIdx.x;

    if (bx < NORM0) {   // ---- convert / pre-pack ----
        int idx = bx * 256 + t;
        if (idx < 589824) {
            wgb[idx] = (h16)wg[idx];
        } else if (idx < 1179648) {
            int i = idx - 589824;
            wbb[i] = (h16)wb[i];
        } else if (idx < 1474560) {
            int i = idx - 1179648;             // wpk[nb][kt][ch][n][e]
            int e  = i & 7;
            int u  = i >> 3;
            int n  = u % 192;
            int v  = u / 192;
            int ch = v & 7;
            int w2 = v >> 3;
            int kt = w2 % 12;
            int nb = w2 / 12;
            int h  = kt * 64 + ch * 8 + e;      // global k
            int ng = nb * 192 + n;              // global col
            int head = ng >> 7, m = ng & 127;
            const float* src = (head == 0) ? we : (head == 1 ? wh : wt);
            wpk[i] = (h16)src[h * 128 + m];
        } else if (idx < 1474944) {
            int n = idx - 1474560;
            biasc[n] = (n < 128) ? be[n] : (n < 256 ? bh[n - 128] : bt[n - 256]);
        }
        return;
    }
    // ---- normalize ----
    const int row = bx - NORM0;
    const int lane = t & 63, wid = t >> 6;
    const float* x = seq + (size_t)row * H_;
    float x0 = x[t], x1 = x[t + 256], x2 = x[t + 512];

    float s = x0 + x1 + x2;
    for (int o = 32; o; o >>= 1) s += __shfl_xor(s, o);
    if (lane == 0) red[wid] = s;
    __syncthreads();
    float mean = (red[0] + red[1] + red[2] + red[3]) * (1.0f / 768.0f);

    float c0 = x0 - mean, c1 = x1 - mean, c2 = x2 - mean;
    float ss = c0 * c0 + c1 * c1 + c2 * c2;
    for (int o = 32; o; o >>= 1) ss += __shfl_xor(ss, o);
    __syncthreads();
    if (lane == 0) red[wid] = ss;
    __syncthreads();
    float var = (red[0] + red[1] + red[2] + red[3]) * (1.0f / 768.0f);
    float sd = var + EPSF;
    float scale = 1.0f / (sd * sd);

    h16* xr = xn + (size_t)row * H_;
    h16* cr = condb + (size_t)row * H_;
    xr[t] = (h16)(c0 * scale); xr[t + 256] = (h16)(c1 * scale); xr[t + 512] = (h16)(c2 * scale);
    cr[t] = (h16)x0;           cr[t + 256] = (h16)x1;           cr[t + 512] = (h16)x2;
}

// ============ kernel B: cond GEMM -> gamma_c / beta_c (f16) ============
// C[p][o] = sum_h cond[p][h] * W[o][h] + bias[o];  tiles 64x64, BK=64
// grid (16, 24): by<12 -> gamma cols by*64 ; else beta cols (by-12)*64
// LDS stride 72 h16 = 144 B: addr%128 takes 8 values over 16 rows -> conflict-free
__global__ __launch_bounds__(256) void k_cond_gemm(
    const h16* __restrict__ Ab, const h16* __restrict__ Wg, const h16* __restrict__ Wb,
    const float* __restrict__ gamma, const float* __restrict__ beta,
    h16* __restrict__ Gc, h16* __restrict__ Bc)
{
    __shared__ h16 Ash[64 * 72];
    __shared__ h16 Bsh[64 * 72];
    const int t = threadIdx.x;
    const int row0 = blockIdx.x * 64;
    const int by = blockIdx.y;
    const bool isg = (by < 12);
    const int nc0 = (isg ? by : by - 12) * 64;
    const h16* wsrc = isg ? Wg : Wb;

    const int r = t >> 2, q = t & 3;
    const h16* ap = Ab + (size_t)(row0 + r) * H_ + q * 16;
    const h16* wp = wsrc + (size_t)(nc0 + r) * H_ + q * 16;
    h16* asto = &Ash[r * 72 + q * 16];
    h16* bsto = &Bsh[r * 72 + q * 16];

    const int lane = t & 63, wid = t >> 6;
    const int wm0 = (wid >> 1) * 32, wn0 = (wid & 1) * 32;
    const int l15 = lane & 15, quad = lane >> 4, q8 = quad * 8;

    f32x4 acc[2][2] = {};
    for (int kt = 0; kt < 12; ++kt) {
        const int k0 = kt * 64;
        uint4 a0 = *(const uint4*)(ap + k0); uint4 a1 = *(const uint4*)(ap + k0 + 8);
        uint4 w0 = *(const uint4*)(wp + k0); uint4 w1 = *(const uint4*)(wp + k0 + 8);
        *(uint4*)asto = a0; *(uint4*)(asto + 8) = a1;
        *(uint4*)bsto = w0; *(uint4*)(bsto + 8) = w1;
        __syncthreads();
#pragma unroll
        for (int ks = 0; ks < 64; ks += 32) {
            ffrag af[2], bf[2];
#pragma unroll
            for (int mi = 0; mi < 2; ++mi)
                af[mi] = *reinterpret_cast<const ffrag*>(&Ash[(wm0 + mi * 16 + l15) * 72 + ks + q8]);
#pragma unroll
            for (int ni = 0; ni < 2; ++ni)
                bf[ni] = *reinterpret_cast<const ffrag*>(&Bsh[(wn0 + ni * 16 + l15) * 72 + ks + q8]);
#pragma unroll
            for (int mi = 0; mi < 2; ++mi)
#pragma unroll
                for (int ni = 0; ni < 2; ++ni)
                    acc[mi][ni] = __builtin_amdgcn_mfma_f32_16x16x32_f16(af[mi], bf[ni], acc[mi][ni], 0, 0, 0);
        }
        __syncthreads();
    }

    const float* bias = isg ? gamma : beta;
    h16* outp = isg ? Gc : Bc;
#pragma unroll
    for (int mi = 0; mi < 2; ++mi)
#pragma unroll
        for (int ni = 0; ni < 2; ++ni) {
            int c = wn0 + ni * 16 + l15;
            float bv = bias[nc0 + c];
#pragma unroll
            for (int reg = 0; reg < 4; ++reg) {
                int rg = wm0 + mi * 16 + quad * 4 + reg;   // C/D: col=lane&15, row=quad*4+reg (m89)
                outp[(size_t)(row0 + rg) * H_ + nc0 + c] = (h16)(acc[mi][ni][reg] + bv);
            }
        }
}

// ============ kernel C: fused pair GEMM ============
// out[head, gp, m] = tanh( (xn[b,j]*gc[b,i] + bc[b,i]) @ W[:, cg] + biasc[cg] )
// Block 64 rows x 192 cols, BK=64, 12 iters, double-buffered.
// v3 (txn-bound fix): B comes from wpk — pre-packed 24KB contiguous tile
// images in exact LDS slot order, so each of the 6 global_load_lds per
// thread-iter covers 1024 contiguous bytes per wave (8 lines, was 64).
// BK=64 makes each A-load 32B/thread/array -> 4 threads fetch one FULL
// 128B line per row; every A byte is fetched exactly once per block
// (was 24 separate 64B half-line touches per row).
// LDS chunk-major: slot(ch,row)=(ch*ROWS+row)*8 h16, ch = k-octet in [0,8).
__global__ __launch_bounds__(256, 2) void k_pair_gemm(
    const h16* __restrict__ Xn, const h16* __restrict__ Gcb, const h16* __restrict__ Bcb,
    const h16* __restrict__ Wpk, const float* __restrict__ biasc,
    float* __restrict__ out)
{
    __shared__ h16 Ash[2][8 * 64 * 8];    // 8 KB per buf
    __shared__ h16 Bsh[2][8 * 192 * 8];   // 24 KB per buf
    __shared__ int offx[64];              // xn row index (b*128 + j)
    __shared__ int offc[64];              // cond row index (b*128 + i)

    const int t = threadIdx.x;
    const int row0 = blockIdx.x * 64;
    const int nb = blockIdx.y;            // 0/1 -> cols [0,192) / [192,384)

    if (t < 64) {
        int gp = row0 + t;
        int b = gp / P_;
        int p = gp - b * P_;
        int i = (int)((257.0f - sqrtf(66049.0f - 8.0f * (float)p)) * 0.5f);
        if (i < 0) i = 0; if (i > 127) i = 127;
        while (i > 0 && (i * (257 - i)) / 2 > p) --i;
        while (((i + 1) * (256 - i)) / 2 <= p) ++i;
        int j = i + (p - (i * (257 - i)) / 2);
        offx[t] = b * 128 + j;
        offc[t] = b * 128 + i;
    }
    __syncthreads();

    // A staging: thread covers row r=t>>2, k-window [c4*16, c4*16+16) of each
    // 64-k tile = chunks 2*c4, 2*c4+1 (two adjacent uint4 loads = 32B/array)
    const int r = t >> 2, c4 = t & 3;
    const h16* xp  = Xn  + (size_t)offx[r] * H_ + c4 * 16;
    const h16* gp_ = Gcb + (size_t)offc[r] * H_ + c4 * 16;
    const h16* bp_ = Bcb + (size_t)offc[r] * H_ + c4 * 16;
    const int aw0 = ((2 * c4) * 64 + r) * 8;
    const int aw1 = ((2 * c4 + 1) * 64 + r) * 8;

    // B DMA: prepacked tile for (nb,kt) is 12288 h16 contiguous, in slot order
    const h16* wtile = Wpk + (size_t)nb * 12 * 12288;
    const int wud = t & ~63;              // wave-uniform slot base

    const int lane = t & 63, wid = t >> 6;
    const int wn0 = wid * 48;             // 4 waves x 48 cols
    const int l15 = lane & 15, quad = lane >> 4;

    // ---------- prologue: stage kt=0 into buffer 0 ----------
#pragma unroll
    for (int c = 0; c < 6; ++c)
        gl_lds16(wtile + (size_t)(c * 256 + t) * 8, &Bsh[0][(c * 256 + wud) * 8]);
    {
        uint4 xa = *(const uint4*)xp;   uint4 xb = *(const uint4*)(xp + 8);
        uint4 ga = *(const uint4*)gp_;  uint4 gb = *(const uint4*)(gp_ + 8);
        uint4 ba = *(const uint4*)bp_;  uint4 bb = *(const uint4*)(bp_ + 8);
        uint4 f0, f1;
        f0.x = fuse2(xa.x, ga.x, ba.x); f0.y = fuse2(xa.y, ga.y, ba.y);
        f0.z = fuse2(xa.z, ga.z, ba.z); f0.w = fuse2(xa.w, ga.w, ba.w);
        f1.x = fuse2(xb.x, gb.x, bb.x); f1.y = fuse2(xb.y, gb.y, bb.y);
        f1.z = fuse2(xb.z, gb.z, bb.z); f1.w = fuse2(xb.w, gb.w, bb.w);
        *(uint4*)&Ash[0][aw0] = f0; *(uint4*)&Ash[0][aw1] = f1;
    }
    __syncthreads();

    f32x4 acc[4][3] = {};
#pragma unroll 2
    for (int kt = 0; kt < 12; ++kt) {
        const int buf = kt & 1, nbf = buf ^ 1;
        uint4 xa, xb, ga, gb, ba, bb;
        if (kt < 11) {
            // next-B DMA first (longest latency), then next-A loads
            const h16* wnext = wtile + (size_t)(kt + 1) * 12288;
#pragma unroll
            for (int c = 0; c < 6; ++c)
                gl_lds16(wnext + (size_t)(c * 256 + t) * 8, &Bsh[nbf][(c * 256 + wud) * 8]);
            const int k0 = (kt + 1) * 64;
            xa = *(const uint4*)(xp + k0);  xb = *(const uint4*)(xp + k0 + 8);
            ga = *(const uint4*)(gp_ + k0); gb = *(const uint4*)(gp_ + k0 + 8);
            ba = *(const uint4*)(bp_ + k0); bb = *(const uint4*)(bp_ + k0 + 8);
        }

#pragma unroll
        for (int ks = 0; ks < 64; ks += 32) {
            const int ch0 = ks >> 3;      // 0 or 4
            ffrag af[4], bf[3];
#pragma unroll
            for (int mi = 0; mi < 4; ++mi)
                af[mi] = *reinterpret_cast<const ffrag*>(
                    &Ash[buf][((ch0 + quad) * 64 + mi * 16 + l15) * 8]);
#pragma unroll
            for (int ni = 0; ni < 3; ++ni)
                bf[ni] = *reinterpret_cast<const ffrag*>(
                    &Bsh[buf][((ch0 + quad) * 192 + wn0 + ni * 16 + l15) * 8]);
#pragma unroll
            for (int mi = 0; mi < 4; ++mi)
#pragma unroll
                for (int ni = 0; ni < 3; ++ni)
                    acc[mi][ni] = __builtin_amdgcn_mfma_f32_16x16x32_f16(af[mi], bf[ni], acc[mi][ni], 0, 0, 0);
        }

        if (kt < 11) {
            uint4 f0, f1;
            f0.x = fuse2(xa.x, ga.x, ba.x); f0.y = fuse2(xa.y, ga.y, ba.y);
            f0.z = fuse2(xa.z, ga.z, ba.z); f0.w = fuse2(xa.w, ga.w, ba.w);
            f1.x = fuse2(xb.x, gb.x, bb.x); f1.y = fuse2(xb.y, gb.y, bb.y);
            f1.z = fuse2(xb.z, gb.z, bb.z); f1.w = fuse2(xb.w, gb.w, bb.w);
            *(uint4*)&Ash[nbf][aw0] = f0; *(uint4*)&Ash[nbf][aw1] = f1;
        }
        __syncthreads();
    }

    // epilogue: bias + tanh + store
#pragma unroll
    for (int mi = 0; mi < 4; ++mi)
#pragma unroll
        for (int ni = 0; ni < 3; ++ni) {
            int cg = nb * 192 + wn0 + ni * 16 + l15;
            int head = cg >> 7, m = cg & 127;
            float bv = biasc[cg];
#pragma unroll
            for (int reg = 0; reg < 4; ++reg) {
                int rg = mi * 16 + quad * 4 + reg;
                out[((size_t)head * BP_ + row0 + rg) * M_ + m] = fast_tanh(acc[mi][ni][reg] + bv);
            }
        }
}

extern "C" void kernel_launch(void* const* d_in, const int* in_sizes, int n_in,
                              void* d_out, int out_size, void* d_ws, size_t ws_size,
                              hipStream_t stream)
{
    const float* seq     = (const float*)d_in[0];
    const float* gamma   = (const float*)d_in[1];
    const float* beta    = (const float*)d_in[2];
    const float* w_beta  = (const float*)d_in[3];
    const float* w_gamma = (const float*)d_in[4];
    const float* w_ent   = (const float*)d_in[5];
    const float* b_ent   = (const float*)d_in[6];
    const float* w_head  = (const float*)d_in[7];
    const float* b_head  = (const float*)d_in[8];
    const float* w_tail  = (const float*)d_in[9];
    const float* b_tail  = (const float*)d_in[10];
    float* out = (float*)d_out;

    // workspace layout (all 16B-aligned)
    char* ws = (char*)d_ws;
    h16* xn    = (h16*)ws; ws += (size_t)1024 * 768 * 2;  // normalized rows, f16
    h16* condb = (h16*)ws; ws += (size_t)1024 * 768 * 2;  // seq as f16
    h16* wgb   = (h16*)ws; ws += (size_t)768 * 768 * 2;   // w_gamma f16 [o][h]
    h16* wbb   = (h16*)ws; ws += (size_t)768 * 768 * 2;   // w_beta  f16 [o][h]
    h16* wpk   = (h16*)ws; ws += (size_t)294912 * 2;      // pre-packed B tiles
    h16* gc    = (h16*)ws; ws += (size_t)1024 * 768 * 2;  // gamma_c f16
    h16* bc    = (h16*)ws; ws += (size_t)1024 * 768 * 2;  // beta_c  f16
    float* biasc = (float*)ws; ws += 384 * 4;             // [ent|head|tail] bias

    hipLaunchKernelGGL(k_prep, dim3(NORM0 + 1024), dim3(256), 0, stream,
                       seq, w_gamma, w_beta, w_ent, w_head, w_tail,
                       b_ent, b_head, b_tail, wgb, wbb, wpk, biasc, xn, condb);
    hipLaunchKernelGGL(k_cond_gemm, dim3(16, 24), dim3(256), 0, stream,
                       condb, wgb, wbb, gamma, beta, gc, bc);
    hipLaunchKernelGGL(k_pair_gemm, dim3(1032, 2), dim3(256), 0, stream,
                       xn, gc, bc, wpk, biasc, out);
}

// Round 3
// 200.461 us; speedup vs baseline: 1.2488x; 1.0603x over previous
//
#include <hip/hip_runtime.h>
#include <hip/hip_bf16.h>
#include <hip/hip_fp16.h>
#include <math.h>

// Problem constants (B,S,H,M) = (8,128,768,128)
#define B_   8
#define S_   128
#define H_   768
#define M_   128
#define P_   8256      // S*(S+1)/2 pairs per batch
#define BP_  66048     // B_ * P_
#define EPSF 1e-12f

typedef unsigned short u16;
typedef unsigned int   u32;
typedef _Float16 h16;
typedef _Float16 ffrag __attribute__((ext_vector_type(8)));   // 8 f16 = 4 VGPR
typedef float    f32x4 __attribute__((ext_vector_type(4)));

// packed f16 fma: one v_pk_fma_f16 for two lanes
__device__ __forceinline__ u32 fuse2(u32 x, u32 g, u32 b) {
    __half2 r = __hfma2(__builtin_bit_cast(__half2, x),
                        __builtin_bit_cast(__half2, g),
                        __builtin_bit_cast(__half2, b));
    return __builtin_bit_cast(u32, r);
}
// tanh(x) = 1 - 2/(e^{2x}+1): exp + rcp + fma, branch/copysign-free,
// correct at +-inf (rcp(inf)=0 -> 1; exp(-inf)=0 -> -1)
__device__ __forceinline__ float fast_tanh(float v) {
    float t = __expf(v + v);
    float r = __builtin_amdgcn_rcpf(t + 1.0f);
    return fmaf(-2.0f, r, 1.0f);
}
// async global->LDS 16B per lane; lds dst must be the wave-uniform base
__device__ __forceinline__ void gl_lds16(const h16* g, h16* l) {
    __builtin_amdgcn_global_load_lds(
        (const __attribute__((address_space(1))) u32*)g,
        (__attribute__((address_space(3))) u32*)l, 16, 0, 0);
}

// ============ kernel A: weight convert + B-prepack + per-row normalize ============
// blocks [0,5763): convert fp32 weights -> f16:
//   [0,589824)          wgb  = w_gamma f16
//   [589824,1179648)    wbb  = w_beta  f16
//   [1179648,1474560)   wpk  = pre-packed pair-GEMM B tiles, BN=128:
//                       wpk[nb][kt][ch][n][e] = w_nb[(kt*64+ch*8+e)*128 + n]
//                       (16KB contiguous image per (nb,kt), exact LDS slot
//                       order -> pair-GEMM B DMA fully coalesced)
//   [1474560,1474944)   biasc
// blocks [5763, 5763+1024): row normalize; xn = (x-mean)/(var+eps)^2
#define NORM0 5763
__global__ void k_prep(const float* __restrict__ seq,
                       const float* __restrict__ wg, const float* __restrict__ wb,
                       const float* __restrict__ we, const float* __restrict__ wh,
                       const float* __restrict__ wt,
                       const float* __restrict__ be, const float* __restrict__ bh,
                       const float* __restrict__ bt,
                       h16* __restrict__ wgb, h16* __restrict__ wbb,
                       h16* __restrict__ wpk, float* __restrict__ biasc,
                       h16* __restrict__ xn, h16* __restrict__ condb)
{
    __shared__ float red[4];
    const int bx = blockIdx.x;
    const int t = threadIdx.x;

    if (bx < NORM0) {   // ---- convert / pre-pack ----
        int idx = bx * 256 + t;
        if (idx < 589824) {
            wgb[idx] = (h16)wg[idx];
        } else if (idx < 1179648) {
            int i = idx - 589824;
            wbb[i] = (h16)wb[i];
        } else if (idx < 1474560) {
            int i = idx - 1179648;             // wpk[nb][kt][ch][n][e]
            int e  = i & 7;
            int n  = (i >> 3) & 127;
            int v  = i >> 10;                  // [0,288)
            int ch = v & 7;
            int w2 = v >> 3;                   // [0,36)
            int kt = w2 % 12;
            int nb = w2 / 12;
            int h  = kt * 64 + ch * 8 + e;     // global k
            const float* src = (nb == 0) ? we : (nb == 1 ? wh : wt);
            wpk[i] = (h16)src[h * 128 + n];
        } else if (idx < 1474944) {
            int n = idx - 1474560;
            biasc[n] = (n < 128) ? be[n] : (n < 256 ? bh[n - 128] : bt[n - 256]);
        }
        return;
    }
    // ---- normalize ----
    const int row = bx - NORM0;
    const int lane = t & 63, wid = t >> 6;
    const float* x = seq + (size_t)row * H_;
    float x0 = x[t], x1 = x[t + 256], x2 = x[t + 512];

    float s = x0 + x1 + x2;
    for (int o = 32; o; o >>= 1) s += __shfl_xor(s, o);
    if (lane == 0) red[wid] = s;
    __syncthreads();
    float mean = (red[0] + red[1] + red[2] + red[3]) * (1.0f / 768.0f);

    float c0 = x0 - mean, c1 = x1 - mean, c2 = x2 - mean;
    float ss = c0 * c0 + c1 * c1 + c2 * c2;
    for (int o = 32; o; o >>= 1) ss += __shfl_xor(ss, o);
    __syncthreads();
    if (lane == 0) red[wid] = ss;
    __syncthreads();
    float var = (red[0] + red[1] + red[2] + red[3]) * (1.0f / 768.0f);
    float sd = var + EPSF;
    float scale = 1.0f / (sd * sd);

    h16* xr = xn + (size_t)row * H_;
    h16* cr = condb + (size_t)row * H_;
    xr[t] = (h16)(c0 * scale); xr[t + 256] = (h16)(c1 * scale); xr[t + 512] = (h16)(c2 * scale);
    cr[t] = (h16)x0;           cr[t + 256] = (h16)x1;           cr[t + 512] = (h16)x2;
}

// ============ kernel B: cond GEMM -> gamma_c / beta_c (f16) ============
// C[p][o] = sum_h cond[p][h] * W[o][h] + bias[o];  tiles 64x64, BK=64
// grid (16, 24): by<12 -> gamma cols by*64 ; else beta cols (by-12)*64
// LDS stride 72 h16 = 144 B: addr%128 takes 8 values over 16 rows -> conflict-free
__global__ __launch_bounds__(256) void k_cond_gemm(
    const h16* __restrict__ Ab, const h16* __restrict__ Wg, const h16* __restrict__ Wb,
    const float* __restrict__ gamma, const float* __restrict__ beta,
    h16* __restrict__ Gc, h16* __restrict__ Bc)
{
    __shared__ h16 Ash[64 * 72];
    __shared__ h16 Bsh[64 * 72];
    const int t = threadIdx.x;
    const int row0 = blockIdx.x * 64;
    const int by = blockIdx.y;
    const bool isg = (by < 12);
    const int nc0 = (isg ? by : by - 12) * 64;
    const h16* wsrc = isg ? Wg : Wb;

    const int r = t >> 2, q = t & 3;
    const h16* ap = Ab + (size_t)(row0 + r) * H_ + q * 16;
    const h16* wp = wsrc + (size_t)(nc0 + r) * H_ + q * 16;
    h16* asto = &Ash[r * 72 + q * 16];
    h16* bsto = &Bsh[r * 72 + q * 16];

    const int lane = t & 63, wid = t >> 6;
    const int wm0 = (wid >> 1) * 32, wn0 = (wid & 1) * 32;
    const int l15 = lane & 15, quad = lane >> 4, q8 = quad * 8;

    f32x4 acc[2][2] = {};
    for (int kt = 0; kt < 12; ++kt) {
        const int k0 = kt * 64;
        uint4 a0 = *(const uint4*)(ap + k0); uint4 a1 = *(const uint4*)(ap + k0 + 8);
        uint4 w0 = *(const uint4*)(wp + k0); uint4 w1 = *(const uint4*)(wp + k0 + 8);
        *(uint4*)asto = a0; *(uint4*)(asto + 8) = a1;
        *(uint4*)bsto = w0; *(uint4*)(bsto + 8) = w1;
        __syncthreads();
#pragma unroll
        for (int ks = 0; ks < 64; ks += 32) {
            ffrag af[2], bf[2];
#pragma unroll
            for (int mi = 0; mi < 2; ++mi)
                af[mi] = *reinterpret_cast<const ffrag*>(&Ash[(wm0 + mi * 16 + l15) * 72 + ks + q8]);
#pragma unroll
            for (int ni = 0; ni < 2; ++ni)
                bf[ni] = *reinterpret_cast<const ffrag*>(&Bsh[(wn0 + ni * 16 + l15) * 72 + ks + q8]);
#pragma unroll
            for (int mi = 0; mi < 2; ++mi)
#pragma unroll
                for (int ni = 0; ni < 2; ++ni)
                    acc[mi][ni] = __builtin_amdgcn_mfma_f32_16x16x32_f16(af[mi], bf[ni], acc[mi][ni], 0, 0, 0);
        }
        __syncthreads();
    }

    const float* bias = isg ? gamma : beta;
    h16* outp = isg ? Gc : Bc;
#pragma unroll
    for (int mi = 0; mi < 2; ++mi)
#pragma unroll
        for (int ni = 0; ni < 2; ++ni) {
            int c = wn0 + ni * 16 + l15;
            float bv = bias[nc0 + c];
#pragma unroll
            for (int reg = 0; reg < 4; ++reg) {
                int rg = wm0 + mi * 16 + quad * 4 + reg;   // C/D: col=lane&15, row=quad*4+reg (m89)
                outp[(size_t)(row0 + rg) * H_ + nc0 + c] = (h16)(acc[mi][ni][reg] + bv);
            }
        }
}

// ============ kernel C: fused pair GEMM ============
// out[head, gp, m] = tanh( (xn[b,j]*gc[b,i] + bc[b,i]) @ W[:, cg] + biasc[cg] )
// v4: Block 128 rows x 128 cols, BK=64, 12 iters, double-buffered.
// Rationale (r2 post-mortem): structure is latency-bound at the per-iter
// barrier; the lever that works is MORE COMPUTE PER BARRIER. BM 64->128
// doubles MFMA per iter (32/wave-iter, acc[4][4]), halves total barrier
// count (18576 vs 24768 block-iters), halves B DMA traffic (B reused by
// 128 rows), MFMA:ds_read ratio 1.71->2.0. LDS 64 KB -> 2 blocks/CU.
// offx/offc LDS tables removed: each thread decodes its own staging row.
// LDS chunk-major: slot(ch,row)=(ch*128+row)*8 h16; B DMA coalesced from
// prepacked wpk (16KB contiguous per (nb,kt), 4 x 1024B wave-instrs).
__global__ __launch_bounds__(256, 2) void k_pair_gemm(
    const h16* __restrict__ Xn, const h16* __restrict__ Gcb, const h16* __restrict__ Bcb,
    const h16* __restrict__ Wpk, const float* __restrict__ biasc,
    float* __restrict__ out)
{
    __shared__ h16 Ash[2][8 * 128 * 8];   // 16 KB per buf
    __shared__ h16 Bsh[2][8 * 128 * 8];   // 16 KB per buf

    const int t = threadIdx.x;
    const int row0 = blockIdx.x * 128;
    const int nb = blockIdx.y;            // 0..2 -> cols nb*128

    // ---- per-thread staging-row decode (row r_s, k-half `half`) ----
    const int r_s = t >> 1, half = t & 1;
    int gp = row0 + r_s;
    int b = gp / P_;
    int p = gp - b * P_;
    int i = (int)((257.0f - sqrtf(66049.0f - 8.0f * (float)p)) * 0.5f);
    if (i < 0) i = 0; if (i > 127) i = 127;
    while (i > 0 && (i * (257 - i)) / 2 > p) --i;
    while (((i + 1) * (256 - i)) / 2 <= p) ++i;
    int j = i + (p - (i * (257 - i)) / 2);

    const h16* xp  = Xn  + (size_t)(b * 128 + j) * H_ + half * 32;
    const h16* gp_ = Gcb + (size_t)(b * 128 + i) * H_ + half * 32;
    const h16* bp_ = Bcb + (size_t)(b * 128 + i) * H_ + half * 32;
    int aw[4];
#pragma unroll
    for (int u = 0; u < 4; ++u)
        aw[u] = ((half * 4 + u) * 128 + r_s) * 8;

    // B DMA: prepacked tile for (nb,kt) is 8192 h16 contiguous, slot order
    const h16* wtile = Wpk + (size_t)nb * 12 * 8192;
    const int wud = t & ~63;              // wave-uniform slot base

    const int lane = t & 63, wid = t >> 6;
    const int wm0 = (wid >> 1) * 64, wn0 = (wid & 1) * 64;
    const int l15 = lane & 15, quad = lane >> 4;

    // ---------- prologue: stage kt=0 into buffer 0 ----------
#pragma unroll
    for (int c = 0; c < 4; ++c)
        gl_lds16(wtile + (size_t)(c * 256 + t) * 8, &Bsh[0][(c * 256 + wud) * 8]);
    {
        uint4 xa[4], ga[4], ba[4];
#pragma unroll
        for (int u = 0; u < 4; ++u) {
            xa[u] = *(const uint4*)(xp + u * 8);
            ga[u] = *(const uint4*)(gp_ + u * 8);
            ba[u] = *(const uint4*)(bp_ + u * 8);
        }
#pragma unroll
        for (int u = 0; u < 4; ++u) {
            uint4 f;
            f.x = fuse2(xa[u].x, ga[u].x, ba[u].x); f.y = fuse2(xa[u].y, ga[u].y, ba[u].y);
            f.z = fuse2(xa[u].z, ga[u].z, ba[u].z); f.w = fuse2(xa[u].w, ga[u].w, ba[u].w);
            *(uint4*)&Ash[0][aw[u]] = f;
        }
    }
    __syncthreads();

    f32x4 acc[4][4] = {};
#pragma unroll 2
    for (int kt = 0; kt < 12; ++kt) {
        const int buf = kt & 1, nbf = buf ^ 1;
        uint4 xa[4], ga[4], ba[4];
        if (kt < 11) {
            // next-B DMA first (longest latency), then next-A loads
            const h16* wnext = wtile + (size_t)(kt + 1) * 8192;
#pragma unroll
            for (int c = 0; c < 4; ++c)
                gl_lds16(wnext + (size_t)(c * 256 + t) * 8, &Bsh[nbf][(c * 256 + wud) * 8]);
            const int k0 = (kt + 1) * 64;
#pragma unroll
            for (int u = 0; u < 4; ++u) {
                xa[u] = *(const uint4*)(xp + k0 + u * 8);
                ga[u] = *(const uint4*)(gp_ + k0 + u * 8);
                ba[u] = *(const uint4*)(bp_ + k0 + u * 8);
            }
        }

#pragma unroll
        for (int ks = 0; ks < 64; ks += 32) {
            const int ch0 = ks >> 3;      // 0 or 4
            ffrag af[4], bf[4];
#pragma unroll
            for (int mi = 0; mi < 4; ++mi)
                af[mi] = *reinterpret_cast<const ffrag*>(
                    &Ash[buf][((ch0 + quad) * 128 + wm0 + mi * 16 + l15) * 8]);
#pragma unroll
            for (int ni = 0; ni < 4; ++ni)
                bf[ni] = *reinterpret_cast<const ffrag*>(
                    &Bsh[buf][((ch0 + quad) * 128 + wn0 + ni * 16 + l15) * 8]);
#pragma unroll
            for (int mi = 0; mi < 4; ++mi)
#pragma unroll
                for (int ni = 0; ni < 4; ++ni)
                    acc[mi][ni] = __builtin_amdgcn_mfma_f32_16x16x32_f16(af[mi], bf[ni], acc[mi][ni], 0, 0, 0);
        }

        if (kt < 11) {
#pragma unroll
            for (int u = 0; u < 4; ++u) {
                uint4 f;
                f.x = fuse2(xa[u].x, ga[u].x, ba[u].x); f.y = fuse2(xa[u].y, ga[u].y, ba[u].y);
                f.z = fuse2(xa[u].z, ga[u].z, ba[u].z); f.w = fuse2(xa[u].w, ga[u].w, ba[u].w);
                *(uint4*)&Ash[nbf][aw[u]] = f;
            }
        }
        __syncthreads();
    }

    // epilogue: bias + tanh + store (head == nb, m == col, since BN=128)
#pragma unroll
    for (int mi = 0; mi < 4; ++mi)
#pragma unroll
        for (int ni = 0; ni < 4; ++ni) {
            int c = wn0 + ni * 16 + l15;
            float bv = biasc[nb * 128 + c];
#pragma unroll
            for (int reg = 0; reg < 4; ++reg) {
                int rg = wm0 + mi * 16 + quad * 4 + reg;
                out[((size_t)nb * BP_ + row0 + rg) * M_ + c] = fast_tanh(acc[mi][ni][reg] + bv);
            }
        }
}

extern "C" void kernel_launch(void* const* d_in, const int* in_sizes, int n_in,
                              void* d_out, int out_size, void* d_ws, size_t ws_size,
                              hipStream_t stream)
{
    const float* seq     = (const float*)d_in[0];
    const float* gamma   = (const float*)d_in[1];
    const float* beta    = (const float*)d_in[2];
    const float* w_beta  = (const float*)d_in[3];
    const float* w_gamma = (const float*)d_in[4];
    const float* w_ent   = (const float*)d_in[5];
    const float* b_ent   = (const float*)d_in[6];
    const float* w_head  = (const float*)d_in[7];
    const float* b_head  = (const float*)d_in[8];
    const float* w_tail  = (const float*)d_in[9];
    const float* b_tail  = (const float*)d_in[10];
    float* out = (float*)d_out;

    // workspace layout (all 16B-aligned)
    char* ws = (char*)d_ws;
    h16* xn    = (h16*)ws; ws += (size_t)1024 * 768 * 2;  // normalized rows, f16
    h16* condb = (h16*)ws; ws += (size_t)1024 * 768 * 2;  // seq as f16
    h16* wgb   = (h16*)ws; ws += (size_t)768 * 768 * 2;   // w_gamma f16 [o][h]
    h16* wbb   = (h16*)ws; ws += (size_t)768 * 768 * 2;   // w_beta  f16 [o][h]
    h16* wpk   = (h16*)ws; ws += (size_t)294912 * 2;      // pre-packed B tiles (3 x 12 x 16KB)
    h16* gc    = (h16*)ws; ws += (size_t)1024 * 768 * 2;  // gamma_c f16
    h16* bc    = (h16*)ws; ws += (size_t)1024 * 768 * 2;  // beta_c  f16
    float* biasc = (float*)ws; ws += 384 * 4;             // [ent|head|tail] bias

    hipLaunchKernelGGL(k_prep, dim3(NORM0 + 1024), dim3(256), 0, stream,
                       seq, w_gamma, w_beta, w_ent, w_head, w_tail,
                       b_ent, b_head, b_tail, wgb, wbb, wpk, biasc, xn, condb);
    hipLaunchKernelGGL(k_cond_gemm, dim3(16, 24), dim3(256), 0, stream,
                       condb, wgb, wbb, gamma, beta, gc, bc);
    hipLaunchKernelGGL(k_pair_gemm, dim3(516, 3), dim3(256), 0, stream,
                       xn, gc, bc, wpk, biasc, out);
}